// Round 6
// baseline (2407.330 us; speedup 1.0000x reference)
//
#include <hip/hip_runtime.h>

typedef _Float16 h8 __attribute__((ext_vector_type(8)));
typedef _Float16 h4v __attribute__((ext_vector_type(4)));
typedef float f4 __attribute__((ext_vector_type(4)));

// ---------------- workspace layout (bytes) ----------------
constexpr size_t O_W0   = 0;         // layer0 A-frags [wv8][j4][ks6][lane64][8h] = 196608 B
constexpr size_t O_W1   = 196608;    // layer1 A-frags [wv8][j4][ks8][lane64][8h] = 262144 B
constexpr size_t O_B0   = 458752;    // bias0_eff[512] f32 (p = dim*4+gate)
constexpr size_t O_B1   = 460800;    // bias1[512] f32
constexpr size_t O_PE   = 462848;    // peg[1000][512] f32 (pe + bias0 folded)
constexpr size_t O_H1   = 2510848;   // h1_last[512][128] f32
constexpr size_t O_RING = 2772992;   // h0 ring [32 g][32 slot][2048 halfs] = 4 MB
constexpr size_t O_CNT  = 6967296;   // flag[32] (stride 64 int) ; cons at +8192 B
constexpr size_t WS_NEED = 6983680;

// A-block LDS row: [x0 64 | x1 64 | h0a 128 | h0b 128 | pad 8] = 392 halfs
#define SROWA 392
// B-block LDS: chunk buf0 [0,16384), buf1 [16384,32768), h1 rows 16 x 264 at 32768
#define B_H1 32768

__device__ __forceinline__ float sigf(float x) { return 1.0f / (1.0f + __expf(-x)); }
__device__ __forceinline__ float tanhfast(float x) {
  float e = __expf(2.0f * x);
  return 1.0f - 2.0f / (e + 1.0f);
}
__device__ __forceinline__ void bar_lds() {
  asm volatile("s_waitcnt lgkmcnt(0)\n\ts_barrier" ::: "memory");
}
__device__ __forceinline__ void bar_full() {
  asm volatile("s_waitcnt vmcnt(0) lgkmcnt(0)\n\ts_barrier" ::: "memory");
}
__device__ __forceinline__ void poll_ge(int* p, int target) {
  int gd = 0;
  while (__hip_atomic_load(p, __ATOMIC_RELAXED, __HIP_MEMORY_SCOPE_AGENT) < target) {
    __builtin_amdgcn_s_sleep(1);
    if (++gd > 30000000) break;
  }
}
// device-coherent (MALL-level) 8B store: write-through past L2, visible chip-wide
// once vmcnt retires. No "memory" clobber: ordering vs flag is via bar_full.
__device__ __forceinline__ void store_dev8(_Float16* addr, h4v v) {
  asm volatile("global_store_dwordx2 %0, %1, off sc0 sc1"
               :: "v"(addr), "v"(v));
}
// device-coherent 16B load: bypasses (possibly stale) L1/L2, reads coherence point.
__device__ __forceinline__ uint4 load_dev16(const uint4* addr) {
  uint4 r;
  asm volatile("global_load_dwordx4 %0, %1, off sc0 sc1"
               : "=v"(r) : "v"(addr) : "memory");
  return r;
}

// gate-slot permutation: A-frag (wv,j), tile-row m: row = (m&3)*128 + wv*16 + (m>>2)*4 + j
// bias/pe arrays indexed p = dim*4 + gate -> row = (p&3)*128 + (p>>2)

// ---- layer0 combined [x_eff(64) | Whh0(128)] A-fragments ----
__global__ void k_wswz0n(const float* __restrict__ Wgcn, const float* __restrict__ Wte,
                         const float* __restrict__ Wih0, const float* __restrict__ Whh0,
                         _Float16* __restrict__ out) {
  int tid = blockIdx.x * 256 + threadIdx.x;   // < 98304
  int e = tid & 7, lane = (tid >> 3) & 63;
  int fi = tid >> 9;                          // 0..191
  int ks = fi % 6; fi /= 6;
  int j = fi & 3, wv = fi >> 2;
  int m = lane & 15;
  int k = ks * 32 + (lane >> 4) * 8 + e;      // 0..191
  int row = (m & 3) * 128 + wv * 16 + (m >> 2) * 4 + j;
  float v = 0.f;
  if (k < 16) {
    float s = 0.f;
    for (int dd = 0; dd < 64; dd++)
      s += Wgcn[k * 64 + dd] * (Wih0[row * 208 + dd] + Wih0[row * 208 + 64 + dd]);
    v = 0.5f * s;
  } else if (k < 42) {
    float s = 0.f;
    for (int dd = 0; dd < 64; dd++)
      s += Wte[(k - 16) * 64 + dd] * Wih0[row * 208 + 144 + dd];
    v = s;
  } else if (k < 64) {
    v = 0.f;
  } else {
    v = Whh0[row * 128 + (k - 64)];
  }
  out[tid] = (_Float16)v;
}

// ---- layer1 [Wih1 | Whh1] A-fragments (full, all reg-resident in consumer) ----
__global__ void k_wswz1n(const float* __restrict__ Wih1, const float* __restrict__ Whh1,
                         _Float16* __restrict__ out) {
  int tid = blockIdx.x * 256 + threadIdx.x;   // < 131072
  int e = tid & 7, lane = (tid >> 3) & 63;
  int fi = tid >> 9;                          // 0..255
  int ks = fi & 7, j = (fi >> 3) & 3, wv = fi >> 5;
  int m = lane & 15;
  int k = ks * 32 + (lane >> 4) * 8 + e;      // 0..255
  int row = (m & 3) * 128 + wv * 16 + (m >> 2) * 4 + j;
  float v = (k < 128) ? Wih1[row * 128 + k] : Whh1[row * 128 + (k - 128)];
  out[tid] = (_Float16)v;
}

__global__ void k_bias(const float* __restrict__ bih0, const float* __restrict__ bhh0,
                       const float* __restrict__ bgcn, const float* __restrict__ bte,
                       const float* __restrict__ Wih0,
                       const float* __restrict__ bih1, const float* __restrict__ bhh1,
                       float* __restrict__ bias0, float* __restrict__ bias1) {
  int p = threadIdx.x;                        // 512
  int row = (p & 3) * 128 + (p >> 2);
  float s = bih0[row] + bhh0[row];
  for (int dd = 0; dd < 64; dd++)
    s += bgcn[dd] * (Wih0[row * 208 + dd] + Wih0[row * 208 + 64 + dd]);
  for (int dd = 0; dd < 64; dd++)
    s += bte[dd] * Wih0[row * 208 + 144 + dd];
  bias0[p] = s;
  bias1[p] = bih1[row] + bhh1[row];
}

__global__ void k_pe(const float* __restrict__ Wih0, const float* __restrict__ bias0,
                     float* __restrict__ peg) {
  int tid = blockIdx.x * 256 + threadIdx.x;   // < 512000
  int t = tid >> 9, p = tid & 511;
  int row = (p & 3) * 128 + (p >> 2);
  float acc = bias0[p];
  float tf = (float)t;
  #pragma unroll
  for (int i = 0; i < 8; i++) {
    float div = expf(-1.1512925464970228f * (float)i);  // exp(2i * -ln(10000)/16)
    float ang = tf * div;
    acc += sinf(ang) * Wih0[row * 208 + 128 + 2 * i]
         + cosf(ang) * Wih0[row * 208 + 129 + 2 * i];
  }
  peg[tid] = acc;
}

// =======================================================================
// pipelined 2-group LSTM: blocks 0..31 layer0 (A), 32..63 layer1 (B)
// ring slot layout (k-major frags): idx = ((k>>3)*16 + m)*8 + (k&7)
// This round (re-submitted after infra failure): guard poll merged into
// the t&7==7 boundary (one fewer barrier/8 steps; poll latency absorbed
// into bar_full wait), split accumulator chains (x-part vs h-part) to
// cut dependent-MFMA depth 6->4 (A) and 8->4 (B).
// =======================================================================
__global__ __launch_bounds__(512, 1) void k_lstm5(
    const float* __restrict__ xs, const float* __restrict__ xtc,
    const _Float16* __restrict__ w0s, const _Float16* __restrict__ w1s,
    const float* __restrict__ peg, const float* __restrict__ b1g,
    _Float16* __restrict__ ring, int* cnt, float* __restrict__ h1l) {
  __shared__ __align__(16) _Float16 sm[36992];   // 73984 B
  const int tidx = threadIdx.x, lane = tidx & 63, wv = tidx >> 6;
  const int q = lane >> 4, mcol = lane & 15;
  const f4 z4 = {0.f, 0.f, 0.f, 0.f};

  if (blockIdx.x < 32) {
    // ================= A: layer 0 =================
    const int g = blockIdx.x;
    int* flag = cnt + g * 64;
    int* cons = cnt + 2048 + g * 64;
    _Float16* rg = ring + (size_t)g * 65536;

    for (int i = tidx; i < 16 * SROWA; i += 512) sm[i] = (_Float16)0.f;

    h8 wf0[4][6];
    #pragma unroll
    for (int j = 0; j < 4; j++)
      #pragma unroll
      for (int ks = 0; ks < 6; ks++)
        wf0[j][ks] = ((const h8*)w0s)[((wv * 4 + j) * 6 + ks) * 64 + lane];

    float c0[4] = {0.f, 0.f, 0.f, 0.f};
    h8 h0f[4];
    #pragma unroll
    for (int i = 0; i < 4; i++) h0f[i] = (h8)(_Float16)0.f;

    const bool isA = tidx < 64;
    const int sa_row = tidx >> 2, sa_c = (tidx & 3) * 4;
    const bool isB = (tidx >= 64) && (tidx < 272);
    const int t2 = tidx - 64;
    const int tb_row = t2 / 13, tb_c = (t2 - tb_row * 13) * 2;
    _Float16* arow = sm + sa_row * SROWA;
    _Float16* brow = sm + tb_row * SROWA;
    _Float16* srow = sm + mcol * SROWA;

    h4v xe = {(_Float16)0.f, (_Float16)0.f, (_Float16)0.f, (_Float16)0.f};
    _Float16 te0 = (_Float16)0.f, te1 = (_Float16)0.f;
    if (isA) {
      const float* xb = xs + ((size_t)(g * 16 + sa_row) * 1000 + 0) * 32;
      f4 a = *(const f4*)(xb + sa_c), b = *(const f4*)(xb + 16 + sa_c);
      h4v o = {(_Float16)(a[0] + b[0]), (_Float16)(a[1] + b[1]),
               (_Float16)(a[2] + b[2]), (_Float16)(a[3] + b[3])};
      *(h4v*)(arow + sa_c) = o;
      const float* xb1 = xs + ((size_t)(g * 16 + sa_row) * 1000 + 1) * 32;
      f4 a1v = *(const f4*)(xb1 + sa_c), b1v = *(const f4*)(xb1 + 16 + sa_c);
      xe[0] = (_Float16)(a1v[0] + b1v[0]); xe[1] = (_Float16)(a1v[1] + b1v[1]);
      xe[2] = (_Float16)(a1v[2] + b1v[2]); xe[3] = (_Float16)(a1v[3] + b1v[3]);
    }
    if (isB) {
      float2 tv = *(const float2*)(xtc + ((size_t)(g * 16 + tb_row) * 1000 + 0) * 26 + tb_c);
      brow[16 + tb_c] = (_Float16)tv.x; brow[16 + tb_c + 1] = (_Float16)tv.y;
      float2 tv1 = *(const float2*)(xtc + ((size_t)(g * 16 + tb_row) * 1000 + 1) * 26 + tb_c);
      te0 = (_Float16)tv1.x; te1 = (_Float16)tv1.y;
    }
    // peg(t=0) prefetch into regs; pp walks row t+1 (pointer bump)
    f4 pgc[4];
    #pragma unroll
    for (int j = 0; j < 4; j++)
      pgc[j] = *(const f4*)(peg + wv * 64 + q * 16 + j * 4);
    const float* pp = peg + 512 + wv * 64 + q * 16;
    __syncthreads();

    #pragma unroll 1
    for (int t = 0; t < 1000; t++) {
      const int tn = (t < 998) ? t + 2 : 999;
      f4 sA = z4, sB = z4; float2 tvr = {0.f, 0.f};
      if (isA) {
        const float* xb = xs + ((size_t)(g * 16 + sa_row) * 1000 + tn) * 32;
        sA = *(const f4*)(xb + sa_c); sB = *(const f4*)(xb + 16 + sa_c);
      }
      if (isB) tvr = *(const float2*)(xtc + ((size_t)(g * 16 + tb_row) * 1000 + tn) * 26 + tb_c);

      f4 acc[4], ach[4];
      #pragma unroll
      for (int j = 0; j < 4; j++) acc[j] = pgc[j];
      // prefetch peg(t+1); final iteration reads 2KB past peg (h1l region, unused)
      #pragma unroll
      for (int j = 0; j < 4; j++)
        pgc[j] = *(const f4*)(pp + j * 4);
      pp += 512;

      const int xoff = (t & 1) * 64;
      h8 xf0 = *(const h8*)(srow + xoff + q * 8);
      h8 xf1 = *(const h8*)(srow + xoff + 32 + q * 8);
      // x-part chain (depth 2, init = peg)
      #pragma unroll
      for (int j = 0; j < 4; j++)
        acc[j] = __builtin_amdgcn_mfma_f32_16x16x32_f16(wf0[j][0], xf0, acc[j], 0, 0, 0);
      #pragma unroll
      for (int j = 0; j < 4; j++)
        acc[j] = __builtin_amdgcn_mfma_f32_16x16x32_f16(wf0[j][1], xf1, acc[j], 0, 0, 0);
      // h-part chain (depth 4, init = 0), merged in activation
      #pragma unroll
      for (int j = 0; j < 4; j++)
        ach[j] = __builtin_amdgcn_mfma_f32_16x16x32_f16(wf0[j][2], h0f[0], z4, 0, 0, 0);
      #pragma unroll
      for (int ks = 1; ks < 4; ks++)
        #pragma unroll
        for (int j = 0; j < 4; j++)
          ach[j] = __builtin_amdgcn_mfma_f32_16x16x32_f16(wf0[j][2 + ks], h0f[ks], ach[j], 0, 0, 0);

      h4v hv0;
      #pragma unroll
      for (int j = 0; j < 4; j++) {
        float gi = acc[j][0] + ach[j][0], gf = acc[j][1] + ach[j][1];
        float gg = acc[j][2] + ach[j][2], go = acc[j][3] + ach[j][3];
        float cc = sigf(gf) * c0[j] + sigf(gi) * tanhfast(gg);
        c0[j] = cc;
        hv0[j] = (_Float16)(sigf(go) * tanhfast(cc));
      }
      *(h4v*)(srow + 128 + (t & 1) * 128 + wv * 16 + q * 4) = hv0;
      // ring publish (k-major frag layout), device-coherent store
      store_dev8(rg + (size_t)(t & 31) * 2048 +
                 ((size_t)((wv * 2 + (q >> 1)) * 16 + mcol)) * 8 + (q & 1) * 4, hv0);
      // stage x(t+1) from regs
      if (isA) *(h4v*)(arow + ((t + 1) & 1) * 64 + sa_c) = xe;
      if (isB) {
        brow[((t + 1) & 1) * 64 + 16 + tb_c] = te0;
        brow[((t + 1) & 1) * 64 + 16 + tb_c + 1] = te1;
      }
      // consume prefetched x(t+2)
      if (isA) {
        xe[0] = (_Float16)(sA[0] + sB[0]); xe[1] = (_Float16)(sA[1] + sB[1]);
        xe[2] = (_Float16)(sA[2] + sB[2]); xe[3] = (_Float16)(sA[3] + sB[3]);
      }
      if (isB) { te0 = (_Float16)tvr.x; te1 = (_Float16)tvr.y; }

      if ((t & 7) == 7) {
        // ring-full guard for steps t+1..t+8: need cons >= t-23 (32-slot ring).
        // Poll BEFORE the barrier so the MALL latency is absorbed into the
        // barrier wait the other waves pay anyway.
        if (tidx == 0 && t >= 31) poll_ge(cons, t - 23);
        // drain all waves' device-coherent ring stores, then publish progress.
        bar_full();
        if (tidx == 0)
          __hip_atomic_store(flag, t + 1, __ATOMIC_RELAXED, __HIP_MEMORY_SCOPE_AGENT);
      } else {
        bar_lds();
      }
      #pragma unroll
      for (int i = 0; i < 4; i++)
        h0f[i] = *(const h8*)(srow + 128 + (t & 1) * 128 + i * 32 + q * 8);
    }
  } else {
    // ================= B: layer 1 =================
    const int g = blockIdx.x - 32;
    int* flag = cnt + g * 64;
    int* cons = cnt + 2048 + g * 64;
    const _Float16* rg = ring + (size_t)g * 65536;

    for (int i = tidx; i < 4224; i += 512) sm[B_H1 + i] = (_Float16)0.f;

    h8 wf1[4][8];
    #pragma unroll
    for (int j = 0; j < 4; j++)
      #pragma unroll
      for (int ks = 0; ks < 8; ks++)
        wf1[j][ks] = ((const h8*)w1s)[((wv * 4 + j) * 8 + ks) * 64 + lane];
    f4 b1r[4];
    #pragma unroll
    for (int j = 0; j < 4; j++)
      b1r[j] = *(const f4*)(b1g + wv * 64 + q * 16 + j * 4);

    float c1[4] = {0.f, 0.f, 0.f, 0.f};
    _Float16* h1row = sm + B_H1 + mcol * 264;
    uint4 cr[4];

    // prologue: chunk 0
    if (tidx == 0) poll_ge(flag, 8);
    bar_lds();
    {
      const uint4* src = (const uint4*)rg;
      #pragma unroll
      for (int p = 0; p < 4; p++) cr[p] = load_dev16(src + p * 512 + tidx);
      asm volatile("s_waitcnt vmcnt(0)" ::: "memory");
      uint4* dst = (uint4*)sm;
      #pragma unroll
      for (int p = 0; p < 4; p++) dst[p * 512 + tidx] = cr[p];
    }
    #pragma unroll 1
    for (int c = 0; c < 125; c++) {
      if (c < 124 && tidx == 0) poll_ge(flag, 8 * (c + 2));
      bar_lds();   // buf[c&1] stores visible to all waves; poll done
      if (c < 124) {
        const uint4* src = (const uint4*)(rg + (size_t)((8 * (c + 1)) & 31) * 2048);
        #pragma unroll
        for (int p = 0; p < 4; p++) cr[p] = load_dev16(src + p * 512 + tidx);
      }
      _Float16* buf = sm + (c & 1) * 16384;
      #pragma unroll 1
      for (int s = 0; s < 8; s++) {
        const int t = c * 8 + s;
        h8 h0f[4], h1f[4];
        #pragma unroll
        for (int i = 0; i < 4; i++)
          h0f[i] = *(const h8*)(buf + s * 2048 + ((i * 4 + q) * 16 + mcol) * 8);
        #pragma unroll
        for (int i = 0; i < 4; i++)
          h1f[i] = *(const h8*)(h1row + (t & 1) * 128 + i * 32 + q * 8);
        // split chains: a1 = bias + Whh1*h1 (depth 4), a2 = Wih1*h0 (depth 4)
        f4 a1[4] = {b1r[0], b1r[1], b1r[2], b1r[3]};
        f4 a2[4];
        #pragma unroll
        for (int j = 0; j < 4; j++)
          a2[j] = __builtin_amdgcn_mfma_f32_16x16x32_f16(wf1[j][0], h0f[0], z4, 0, 0, 0);
        #pragma unroll
        for (int ks = 0; ks < 4; ks++)
          #pragma unroll
          for (int j = 0; j < 4; j++)
            a1[j] = __builtin_amdgcn_mfma_f32_16x16x32_f16(wf1[j][4 + ks], h1f[ks], a1[j], 0, 0, 0);
        #pragma unroll
        for (int ks = 1; ks < 4; ks++)
          #pragma unroll
          for (int j = 0; j < 4; j++)
            a2[j] = __builtin_amdgcn_mfma_f32_16x16x32_f16(wf1[j][ks], h0f[ks], a2[j], 0, 0, 0);
        h4v hv1; f4 hfv;
        #pragma unroll
        for (int j = 0; j < 4; j++) {
          float gi = a1[j][0] + a2[j][0], gf = a1[j][1] + a2[j][1];
          float gg = a1[j][2] + a2[j][2], go = a1[j][3] + a2[j][3];
          float cc = sigf(gf) * c1[j] + sigf(gi) * tanhfast(gg);
          c1[j] = cc;
          float h = sigf(go) * tanhfast(cc);
          hfv[j] = h;
          hv1[j] = (_Float16)h;
        }
        *(h4v*)(h1row + ((t + 1) & 1) * 128 + wv * 16 + q * 4) = hv1;
        if (t == 999)
          *(f4*)(h1l + (size_t)(g * 16 + mcol) * 128 + wv * 16 + q * 4) = hfv;
        bar_lds();
      }
      if (c < 124) {
        asm volatile("s_waitcnt vmcnt(0)" ::: "memory");
        uint4* dst = (uint4*)(sm + ((c + 1) & 1) * 16384);
        #pragma unroll
        for (int p = 0; p < 4; p++) dst[p * 512 + tidx] = cr[p];
      }
      if (tidx == 0)
        __hip_atomic_store(cons, 8 * (c + 1), __ATOMIC_RELAXED, __HIP_MEMORY_SCOPE_AGENT);
    }
  }
}

// ---- MLP head: one block per batch row ----
__global__ void k_mlp(const float* __restrict__ h1l,
                      const float* __restrict__ W1, const float* __restrict__ b1,
                      const float* __restrict__ W2, const float* __restrict__ b2,
                      const float* __restrict__ W3, const float* __restrict__ b3,
                      float* __restrict__ out) {
  __shared__ float sh[128];
  __shared__ float sy1[128];
  __shared__ float sy2[64];
  const int b = blockIdx.x;
  const int t = threadIdx.x;   // 128 threads
  sh[t] = h1l[b * 128 + t];
  __syncthreads();
  {
    float s = b1[t];
    const float* wr = W1 + t * 128;
    for (int k = 0; k < 128; k++) s += sh[k] * wr[k];
    sy1[t] = fmaxf(s, 0.f);
  }
  __syncthreads();
  if (t < 64) {
    float s = b2[t];
    const float* wr = W2 + t * 128;
    for (int k = 0; k < 128; k++) s += sy1[k] * wr[k];
    sy2[t] = fmaxf(s, 0.f);
  }
  __syncthreads();
  if (t < 26) {
    float s = b3[t];
    const float* wr = W3 + t * 64;
    for (int k = 0; k < 64; k++) s += sy2[k] * wr[k];
    out[b * 26 + t] = s;
  }
}

extern "C" void kernel_launch(void* const* d_in, const int* in_sizes, int n_in,
                              void* d_out, int out_size, void* d_ws, size_t ws_size,
                              hipStream_t stream) {
  const float* xs   = (const float*)d_in[0];
  const float* xtc  = (const float*)d_in[1];
  const float* Wgcn = (const float*)d_in[2];
  const float* bgcn = (const float*)d_in[3];
  const float* Wte  = (const float*)d_in[4];
  const float* bte  = (const float*)d_in[5];
  const float* Wih0 = (const float*)d_in[6];
  const float* Whh0 = (const float*)d_in[7];
  const float* bih0 = (const float*)d_in[8];
  const float* bhh0 = (const float*)d_in[9];
  const float* Wih1 = (const float*)d_in[10];
  const float* Whh1 = (const float*)d_in[11];
  const float* bih1 = (const float*)d_in[12];
  const float* bhh1 = (const float*)d_in[13];
  const float* W1   = (const float*)d_in[14];
  const float* b1   = (const float*)d_in[15];
  const float* W2   = (const float*)d_in[16];
  const float* b2   = (const float*)d_in[17];
  const float* W3   = (const float*)d_in[18];
  const float* b3   = (const float*)d_in[19];

  char* ws = (char*)d_ws;
  if (ws_size < WS_NEED) return;

  _Float16* w0s  = (_Float16*)(ws + O_W0);
  _Float16* w1s  = (_Float16*)(ws + O_W1);
  float* bias0   = (float*)(ws + O_B0);
  float* bias1   = (float*)(ws + O_B1);
  float* peg     = (float*)(ws + O_PE);
  float* h1l     = (float*)(ws + O_H1);
  _Float16* ring = (_Float16*)(ws + O_RING);
  int* cnt       = (int*)(ws + O_CNT);

  hipMemsetAsync(ws + O_CNT, 0, 16384, stream);
  hipLaunchKernelGGL(k_bias, dim3(1), dim3(512), 0, stream, bih0, bhh0, bgcn, bte, Wih0, bih1, bhh1, bias0, bias1);
  hipLaunchKernelGGL(k_pe, dim3(2000), dim3(256), 0, stream, Wih0, bias0, peg);
  hipLaunchKernelGGL(k_wswz0n, dim3(384), dim3(256), 0, stream, Wgcn, Wte, Wih0, Whh0, w0s);
  hipLaunchKernelGGL(k_wswz1n, dim3(512), dim3(256), 0, stream, Wih1, Whh1, w1s);
  hipLaunchKernelGGL(k_lstm5, dim3(64), dim3(512), 0, stream, xs, xtc, w0s, w1s, peg, bias1, ring, cnt, h1l);
  hipLaunchKernelGGL(k_mlp, dim3(512), dim3(128), 0, stream, h1l, W1, b1, W2, b2, W3, b3, (float*)d_out);
}

// Round 9
// 1685.472 us; speedup vs baseline: 1.4283x; 1.4283x over previous
//
#include <hip/hip_runtime.h>

typedef _Float16 h8 __attribute__((ext_vector_type(8)));
typedef _Float16 h4v __attribute__((ext_vector_type(4)));
typedef float f4 __attribute__((ext_vector_type(4)));

// ---------------- workspace layout (bytes) ----------------
constexpr size_t O_W0   = 0;         // layer0 A-frags [wv8][j4][ks6][lane64][8h] = 196608 B
constexpr size_t O_W1   = 196608;    // layer1 A-frags [wv8][j4][ks8][lane64][8h] = 262144 B
constexpr size_t O_B0   = 458752;    // bias0_eff[512] f32 (UNscaled; consumed by k_pe)
constexpr size_t O_B1   = 460800;    // bias1[512] f32 (gate-scaled)
constexpr size_t O_PE   = 462848;    // peg[1000][512] f32 (pe + bias0 folded, gate-scaled)
constexpr size_t O_H1   = 2510848;   // h1_last[512][128] f32
constexpr size_t O_RING = 2772992;   // h0 ring [32 g][32 slot][2048 halfs] = 4 MB
constexpr size_t O_CNT  = 6967296;   // flag[32] (stride 64 int) ; cons at +8192 B
constexpr size_t WS_NEED = 6983680;

// A-block LDS row: [x0 64 | x1 64 | h0a 128 | h0b 128 | pad 8] = 392 halfs
#define SROWA 392
// B-block LDS: chunk buf0 [0,16384), buf1 [16384,32768), h1 rows 16 x 264 at 32768
#define B_H1 32768

// gate scale factors folded into weights/bias/pe (act diet):
//   i,f,o rows: -log2e   (sigma(x) = rcp(1 + 2^z), z = -x*log2e)
//   g rows   : +2*log2e  (tanh(x) = 1 - 2*rcp(2^z + 1), z = 2x*log2e)
#define SG_NEG (-1.4426950408889634f)
#define SG_G   (2.885390081777927f)

__device__ __forceinline__ float rcp_f(float x) {
  float r; asm("v_rcp_f32 %0, %1" : "=v"(r) : "v"(x)); return r;
}
__device__ __forceinline__ float ex2_f(float x) {
  float r; asm("v_exp_f32 %0, %1" : "=v"(r) : "v"(x)); return r;
}
// gates pre-scaled (see above). Updates c, returns h.
__device__ __forceinline__ float cell_up(float zi, float zf, float zg, float zo, float& c) {
  float si = rcp_f(1.f + ex2_f(zi));
  float sf = rcp_f(1.f + ex2_f(zf));
  float tg = __builtin_fmaf(-2.f, rcp_f(1.f + ex2_f(zg)), 1.f);
  float cc = __builtin_fmaf(sf, c, si * tg);
  c = cc;
  float so = rcp_f(1.f + ex2_f(zo));
  float tc = __builtin_fmaf(-2.f, rcp_f(1.f + ex2_f(cc * SG_G)), 1.f);
  return so * tc;
}
__device__ __forceinline__ void bar_lds() {
  asm volatile("s_waitcnt lgkmcnt(0)\n\ts_barrier" ::: "memory");
}
__device__ __forceinline__ void bar_full() {
  asm volatile("s_waitcnt vmcnt(0) lgkmcnt(0)\n\ts_barrier" ::: "memory");
}
__device__ __forceinline__ void poll_ge(int* p, int target) {
  int gd = 0;
  while (__hip_atomic_load(p, __ATOMIC_RELAXED, __HIP_MEMORY_SCOPE_AGENT) < target) {
    __builtin_amdgcn_s_sleep(1);
    if (++gd > 30000000) break;
  }
}
// device-coherent (MALL-level) 8B store: visible chip-wide once vmcnt retires.
__device__ __forceinline__ void store_dev8(_Float16* addr, h4v v) {
  asm volatile("global_store_dwordx2 %0, %1, off sc0 sc1" :: "v"(addr), "v"(v));
}
// device-coherent 16B load: bypasses (possibly stale) L1/L2, reads coherence point.
__device__ __forceinline__ uint4 load_dev16(const uint4* addr) {
  uint4 r;
  asm volatile("global_load_dwordx4 %0, %1, off sc0 sc1" : "=v"(r) : "v"(addr) : "memory");
  return r;
}

// gate-slot permutation: A-frag (wv,j), tile-row m: row = (m&3)*128 + wv*16 + (m>>2)*4 + j
// bias/pe arrays indexed p = dim*4+gate -> row = (p&3)*128 + (p>>2); gate = row>>7 = p&3

// ---- layer0 combined [x_eff(64) | Whh0(128)] A-fragments (gate-scaled) ----
__global__ void k_wswz0n(const float* __restrict__ Wgcn, const float* __restrict__ Wte,
                         const float* __restrict__ Wih0, const float* __restrict__ Whh0,
                         _Float16* __restrict__ out) {
  int tid = blockIdx.x * 256 + threadIdx.x;   // < 98304
  int e = tid & 7, lane = (tid >> 3) & 63;
  int fi = tid >> 9;                          // 0..191
  int ks = fi % 6; fi /= 6;
  int j = fi & 3, wv = fi >> 2;
  int m = lane & 15;
  int k = ks * 32 + (lane >> 4) * 8 + e;      // 0..191
  int row = (m & 3) * 128 + wv * 16 + (m >> 2) * 4 + j;
  float v = 0.f;
  if (k < 16) {
    float s = 0.f;
    for (int dd = 0; dd < 64; dd++)
      s += Wgcn[k * 64 + dd] * (Wih0[row * 208 + dd] + Wih0[row * 208 + 64 + dd]);
    v = 0.5f * s;
  } else if (k < 42) {
    float s = 0.f;
    for (int dd = 0; dd < 64; dd++)
      s += Wte[(k - 16) * 64 + dd] * Wih0[row * 208 + 144 + dd];
    v = s;
  } else if (k < 64) {
    v = 0.f;
  } else {
    v = Whh0[row * 128 + (k - 64)];
  }
  float sg = ((row >> 7) == 2) ? SG_G : SG_NEG;
  out[tid] = (_Float16)(v * sg);
}

// ---- layer1 [Wih1 | Whh1] A-fragments (gate-scaled) ----
__global__ void k_wswz1n(const float* __restrict__ Wih1, const float* __restrict__ Whh1,
                         _Float16* __restrict__ out) {
  int tid = blockIdx.x * 256 + threadIdx.x;   // < 131072
  int e = tid & 7, lane = (tid >> 3) & 63;
  int fi = tid >> 9;                          // 0..255
  int ks = fi & 7, j = (fi >> 3) & 3, wv = fi >> 5;
  int m = lane & 15;
  int k = ks * 32 + (lane >> 4) * 8 + e;      // 0..255
  int row = (m & 3) * 128 + wv * 16 + (m >> 2) * 4 + j;
  float v = (k < 128) ? Wih1[row * 128 + k] : Whh1[row * 128 + (k - 128)];
  float sg = ((row >> 7) == 2) ? SG_G : SG_NEG;
  out[tid] = (_Float16)(v * sg);
}

__global__ void k_bias(const float* __restrict__ bih0, const float* __restrict__ bhh0,
                       const float* __restrict__ bgcn, const float* __restrict__ bte,
                       const float* __restrict__ Wih0,
                       const float* __restrict__ bih1, const float* __restrict__ bhh1,
                       float* __restrict__ bias0, float* __restrict__ bias1) {
  int p = threadIdx.x;                        // 512
  int row = (p & 3) * 128 + (p >> 2);
  float s = bih0[row] + bhh0[row];
  for (int dd = 0; dd < 64; dd++)
    s += bgcn[dd] * (Wih0[row * 208 + dd] + Wih0[row * 208 + 64 + dd]);
  for (int dd = 0; dd < 64; dd++)
    s += bte[dd] * Wih0[row * 208 + 144 + dd];
  bias0[p] = s;   // UNscaled; k_pe applies the gate scale to the total
  float sg = ((p & 3) == 2) ? SG_G : SG_NEG;
  bias1[p] = (bih1[row] + bhh1[row]) * sg;
}

__global__ void k_pe(const float* __restrict__ Wih0, const float* __restrict__ bias0,
                     float* __restrict__ peg) {
  int tid = blockIdx.x * 256 + threadIdx.x;   // < 512000
  int t = tid >> 9, p = tid & 511;
  int row = (p & 3) * 128 + (p >> 2);
  float acc = bias0[p];
  float tf = (float)t;
  #pragma unroll
  for (int i = 0; i < 8; i++) {
    float div = expf(-1.1512925464970228f * (float)i);  // exp(2i * -ln(10000)/16)
    float ang = tf * div;
    acc += sinf(ang) * Wih0[row * 208 + 128 + 2 * i]
         + cosf(ang) * Wih0[row * 208 + 129 + 2 * i];
  }
  float sg = ((p & 3) == 2) ? SG_G : SG_NEG;
  peg[tid] = acc * sg;
}

// =======================================================================
// pipelined 2-group LSTM (the r6-VERIFIED structure): blocks 0..31
// layer0 (A), 32..63 layer1 (B). Only change vs r6: act diet (gate
// scales folded into weights; raw v_exp/v_rcp activations).
// ring slot layout (k-major frags): idx = ((k>>3)*16 + m)*8 + (k&7)
// =======================================================================
__global__ __launch_bounds__(512, 1) void k_lstm5(
    const float* __restrict__ xs, const float* __restrict__ xtc,
    const _Float16* __restrict__ w0s, const _Float16* __restrict__ w1s,
    const float* __restrict__ peg, const float* __restrict__ b1g,
    _Float16* __restrict__ ring, int* cnt, float* __restrict__ h1l) {
  __shared__ __align__(16) _Float16 sm[36992];   // 73984 B
  const int tidx = threadIdx.x, lane = tidx & 63, wv = tidx >> 6;
  const int q = lane >> 4, mcol = lane & 15;
  const f4 z4 = {0.f, 0.f, 0.f, 0.f};

  if (blockIdx.x < 32) {
    // ================= A: layer 0 =================
    const int g = blockIdx.x;
    int* flag = cnt + g * 64;
    int* cons = cnt + 2048 + g * 64;
    _Float16* rg = ring + (size_t)g * 65536;

    for (int i = tidx; i < 16 * SROWA; i += 512) sm[i] = (_Float16)0.f;

    h8 wf0[4][6];
    #pragma unroll
    for (int j = 0; j < 4; j++)
      #pragma unroll
      for (int ks = 0; ks < 6; ks++)
        wf0[j][ks] = ((const h8*)w0s)[((wv * 4 + j) * 6 + ks) * 64 + lane];

    float c0[4] = {0.f, 0.f, 0.f, 0.f};
    h8 h0f[4];
    #pragma unroll
    for (int i = 0; i < 4; i++) h0f[i] = (h8)(_Float16)0.f;

    const bool isA = tidx < 64;
    const int sa_row = tidx >> 2, sa_c = (tidx & 3) * 4;
    const bool isB = (tidx >= 64) && (tidx < 272);
    const int t2 = tidx - 64;
    const int tb_row = t2 / 13, tb_c = (t2 - tb_row * 13) * 2;
    _Float16* arow = sm + sa_row * SROWA;
    _Float16* brow = sm + tb_row * SROWA;
    _Float16* srow = sm + mcol * SROWA;

    h4v xe = {(_Float16)0.f, (_Float16)0.f, (_Float16)0.f, (_Float16)0.f};
    _Float16 te0 = (_Float16)0.f, te1 = (_Float16)0.f;
    if (isA) {
      const float* xb = xs + ((size_t)(g * 16 + sa_row) * 1000 + 0) * 32;
      f4 a = *(const f4*)(xb + sa_c), b = *(const f4*)(xb + 16 + sa_c);
      h4v o = {(_Float16)(a[0] + b[0]), (_Float16)(a[1] + b[1]),
               (_Float16)(a[2] + b[2]), (_Float16)(a[3] + b[3])};
      *(h4v*)(arow + sa_c) = o;
      const float* xb1 = xs + ((size_t)(g * 16 + sa_row) * 1000 + 1) * 32;
      f4 a1v = *(const f4*)(xb1 + sa_c), b1v = *(const f4*)(xb1 + 16 + sa_c);
      xe[0] = (_Float16)(a1v[0] + b1v[0]); xe[1] = (_Float16)(a1v[1] + b1v[1]);
      xe[2] = (_Float16)(a1v[2] + b1v[2]); xe[3] = (_Float16)(a1v[3] + b1v[3]);
    }
    if (isB) {
      float2 tv = *(const float2*)(xtc + ((size_t)(g * 16 + tb_row) * 1000 + 0) * 26 + tb_c);
      brow[16 + tb_c] = (_Float16)tv.x; brow[16 + tb_c + 1] = (_Float16)tv.y;
      float2 tv1 = *(const float2*)(xtc + ((size_t)(g * 16 + tb_row) * 1000 + 1) * 26 + tb_c);
      te0 = (_Float16)tv1.x; te1 = (_Float16)tv1.y;
    }
    // peg(t=0) prefetch into regs; pp walks row t+1 (pointer bump)
    f4 pgc[4];
    #pragma unroll
    for (int j = 0; j < 4; j++)
      pgc[j] = *(const f4*)(peg + wv * 64 + q * 16 + j * 4);
    const float* pp = peg + 512 + wv * 64 + q * 16;
    __syncthreads();

    #pragma unroll 1
    for (int t = 0; t < 1000; t++) {
      const int tn = (t < 998) ? t + 2 : 999;
      f4 sA = z4, sB = z4; float2 tvr = {0.f, 0.f};
      if (isA) {
        const float* xb = xs + ((size_t)(g * 16 + sa_row) * 1000 + tn) * 32;
        sA = *(const f4*)(xb + sa_c); sB = *(const f4*)(xb + 16 + sa_c);
      }
      if (isB) tvr = *(const float2*)(xtc + ((size_t)(g * 16 + tb_row) * 1000 + tn) * 26 + tb_c);

      f4 acc[4], ach[4];
      #pragma unroll
      for (int j = 0; j < 4; j++) acc[j] = pgc[j];
      // prefetch peg(t+1); final iteration reads past peg (h1l region, unused)
      #pragma unroll
      for (int j = 0; j < 4; j++)
        pgc[j] = *(const f4*)(pp + j * 4);
      pp += 512;

      const int xoff = (t & 1) * 64;
      h8 xf0 = *(const h8*)(srow + xoff + q * 8);
      h8 xf1 = *(const h8*)(srow + xoff + 32 + q * 8);
      // x-part chain (depth 2, init = peg)
      #pragma unroll
      for (int j = 0; j < 4; j++)
        acc[j] = __builtin_amdgcn_mfma_f32_16x16x32_f16(wf0[j][0], xf0, acc[j], 0, 0, 0);
      #pragma unroll
      for (int j = 0; j < 4; j++)
        acc[j] = __builtin_amdgcn_mfma_f32_16x16x32_f16(wf0[j][1], xf1, acc[j], 0, 0, 0);
      // h-part chain (depth 4, init = 0), merged in activation
      #pragma unroll
      for (int j = 0; j < 4; j++)
        ach[j] = __builtin_amdgcn_mfma_f32_16x16x32_f16(wf0[j][2], h0f[0], z4, 0, 0, 0);
      #pragma unroll
      for (int ks = 1; ks < 4; ks++)
        #pragma unroll
        for (int j = 0; j < 4; j++)
          ach[j] = __builtin_amdgcn_mfma_f32_16x16x32_f16(wf0[j][2 + ks], h0f[ks], ach[j], 0, 0, 0);

      h4v hv0;
      #pragma unroll
      for (int j = 0; j < 4; j++) {
        float h = cell_up(acc[j][0] + ach[j][0], acc[j][1] + ach[j][1],
                          acc[j][2] + ach[j][2], acc[j][3] + ach[j][3], c0[j]);
        hv0[j] = (_Float16)h;
      }
      *(h4v*)(srow + 128 + (t & 1) * 128 + wv * 16 + q * 4) = hv0;
      // ring publish (k-major frag layout), device-coherent store
      store_dev8(rg + (size_t)(t & 31) * 2048 +
                 ((size_t)((wv * 2 + (q >> 1)) * 16 + mcol)) * 8 + (q & 1) * 4, hv0);
      // stage x(t+1) from regs
      if (isA) *(h4v*)(arow + ((t + 1) & 1) * 64 + sa_c) = xe;
      if (isB) {
        brow[((t + 1) & 1) * 64 + 16 + tb_c] = te0;
        brow[((t + 1) & 1) * 64 + 16 + tb_c + 1] = te1;
      }
      // consume prefetched x(t+2)
      if (isA) {
        xe[0] = (_Float16)(sA[0] + sB[0]); xe[1] = (_Float16)(sA[1] + sB[1]);
        xe[2] = (_Float16)(sA[2] + sB[2]); xe[3] = (_Float16)(sA[3] + sB[3]);
      }
      if (isB) { te0 = (_Float16)tvr.x; te1 = (_Float16)tvr.y; }

      if ((t & 7) == 7) {
        // ring-full guard for steps t+1..t+8: need cons >= t-23 (32-slot ring).
        if (tidx == 0 && t >= 31) poll_ge(cons, t - 23);
        bar_full();
        if (tidx == 0)
          __hip_atomic_store(flag, t + 1, __ATOMIC_RELAXED, __HIP_MEMORY_SCOPE_AGENT);
      } else {
        bar_lds();
      }
      #pragma unroll
      for (int i = 0; i < 4; i++)
        h0f[i] = *(const h8*)(srow + 128 + (t & 1) * 128 + i * 32 + q * 8);
    }
  } else {
    // ================= B: layer 1 =================
    const int g = blockIdx.x - 32;
    int* flag = cnt + g * 64;
    int* cons = cnt + 2048 + g * 64;
    const _Float16* rg = ring + (size_t)g * 65536;

    for (int i = tidx; i < 4224; i += 512) sm[B_H1 + i] = (_Float16)0.f;

    h8 wf1[4][8];
    #pragma unroll
    for (int j = 0; j < 4; j++)
      #pragma unroll
      for (int ks = 0; ks < 8; ks++)
        wf1[j][ks] = ((const h8*)w1s)[((wv * 4 + j) * 8 + ks) * 64 + lane];
    f4 b1r[4];
    #pragma unroll
    for (int j = 0; j < 4; j++)
      b1r[j] = *(const f4*)(b1g + wv * 64 + q * 16 + j * 4);

    float c1[4] = {0.f, 0.f, 0.f, 0.f};
    _Float16* h1row = sm + B_H1 + mcol * 264;
    uint4 cr[4];

    // prologue: chunk 0
    if (tidx == 0) poll_ge(flag, 8);
    bar_lds();
    {
      const uint4* src = (const uint4*)rg;
      #pragma unroll
      for (int p = 0; p < 4; p++) cr[p] = load_dev16(src + p * 512 + tidx);
      asm volatile("s_waitcnt vmcnt(0)" ::: "memory");
      uint4* dst = (uint4*)sm;
      #pragma unroll
      for (int p = 0; p < 4; p++) dst[p * 512 + tidx] = cr[p];
    }
    #pragma unroll 1
    for (int c = 0; c < 125; c++) {
      if (c < 124 && tidx == 0) poll_ge(flag, 8 * (c + 2));
      bar_lds();   // buf[c&1] stores visible to all waves; poll done
      if (c < 124) {
        const uint4* src = (const uint4*)(rg + (size_t)((8 * (c + 1)) & 31) * 2048);
        #pragma unroll
        for (int p = 0; p < 4; p++) cr[p] = load_dev16(src + p * 512 + tidx);
      }
      _Float16* buf = sm + (c & 1) * 16384;
      #pragma unroll 1
      for (int s = 0; s < 8; s++) {
        const int t = c * 8 + s;
        h8 h0f[4], h1f[4];
        #pragma unroll
        for (int i = 0; i < 4; i++)
          h0f[i] = *(const h8*)(buf + s * 2048 + ((i * 4 + q) * 16 + mcol) * 8);
        #pragma unroll
        for (int i = 0; i < 4; i++)
          h1f[i] = *(const h8*)(h1row + (t & 1) * 128 + i * 32 + q * 8);
        // split chains: a1 = bias + Whh1*h1 (depth 4), a2 = Wih1*h0 (depth 4)
        f4 a1[4] = {b1r[0], b1r[1], b1r[2], b1r[3]};
        f4 a2[4];
        #pragma unroll
        for (int j = 0; j < 4; j++)
          a2[j] = __builtin_amdgcn_mfma_f32_16x16x32_f16(wf1[j][0], h0f[0], z4, 0, 0, 0);
        #pragma unroll
        for (int ks = 0; ks < 4; ks++)
          #pragma unroll
          for (int j = 0; j < 4; j++)
            a1[j] = __builtin_amdgcn_mfma_f32_16x16x32_f16(wf1[j][4 + ks], h1f[ks], a1[j], 0, 0, 0);
        #pragma unroll
        for (int ks = 1; ks < 4; ks++)
          #pragma unroll
          for (int j = 0; j < 4; j++)
            a2[j] = __builtin_amdgcn_mfma_f32_16x16x32_f16(wf1[j][ks], h0f[ks], a2[j], 0, 0, 0);
        h4v hv1; f4 hfv;
        #pragma unroll
        for (int j = 0; j < 4; j++) {
          float h = cell_up(a1[j][0] + a2[j][0], a1[j][1] + a2[j][1],
                            a1[j][2] + a2[j][2], a1[j][3] + a2[j][3], c1[j]);
          hfv[j] = h;
          hv1[j] = (_Float16)h;
        }
        *(h4v*)(h1row + ((t + 1) & 1) * 128 + wv * 16 + q * 4) = hv1;
        if (t == 999)
          *(f4*)(h1l + (size_t)(g * 16 + mcol) * 128 + wv * 16 + q * 4) = hfv;
        bar_lds();
      }
      if (c < 124) {
        asm volatile("s_waitcnt vmcnt(0)" ::: "memory");
        uint4* dst = (uint4*)(sm + ((c + 1) & 1) * 16384);
        #pragma unroll
        for (int p = 0; p < 4; p++) dst[p * 512 + tidx] = cr[p];
      }
      if (tidx == 0)
        __hip_atomic_store(cons, 8 * (c + 1), __ATOMIC_RELAXED, __HIP_MEMORY_SCOPE_AGENT);
    }
  }
}

// ---- MLP head: one block per batch row ----
__global__ void k_mlp(const float* __restrict__ h1l,
                      const float* __restrict__ W1, const float* __restrict__ b1,
                      const float* __restrict__ W2, const float* __restrict__ b2,
                      const float* __restrict__ W3, const float* __restrict__ b3,
                      float* __restrict__ out) {
  __shared__ float sh[128];
  __shared__ float sy1[128];
  __shared__ float sy2[64];
  const int b = blockIdx.x;
  const int t = threadIdx.x;   // 128 threads
  sh[t] = h1l[b * 128 + t];
  __syncthreads();
  {
    float s = b1[t];
    const float* wr = W1 + t * 128;
    for (int k = 0; k < 128; k++) s += sh[k] * wr[k];
    sy1[t] = fmaxf(s, 0.f);
  }
  __syncthreads();
  if (t < 64) {
    float s = b2[t];
    const float* wr = W2 + t * 128;
    for (int k = 0; k < 128; k++) s += sy1[k] * wr[k];
    sy2[t] = fmaxf(s, 0.f);
  }
  __syncthreads();
  if (t < 26) {
    float s = b3[t];
    const float* wr = W3 + t * 64;
    for (int k = 0; k < 64; k++) s += sy2[k] * wr[k];
    out[b * 26 + t] = s;
  }
}

extern "C" void kernel_launch(void* const* d_in, const int* in_sizes, int n_in,
                              void* d_out, int out_size, void* d_ws, size_t ws_size,
                              hipStream_t stream) {
  const float* xs   = (const float*)d_in[0];
  const float* xtc  = (const float*)d_in[1];
  const float* Wgcn = (const float*)d_in[2];
  const float* bgcn = (const float*)d_in[3];
  const float* Wte  = (const float*)d_in[4];
  const float* bte  = (const float*)d_in[5];
  const float* Wih0 = (const float*)d_in[6];
  const float* Whh0 = (const float*)d_in[7];
  const float* bih0 = (const float*)d_in[8];
  const float* bhh0 = (const float*)d_in[9];
  const float* Wih1 = (const float*)d_in[10];
  const float* Whh1 = (const float*)d_in[11];
  const float* bih1 = (const float*)d_in[12];
  const float* bhh1 = (const float*)d_in[13];
  const float* W1   = (const float*)d_in[14];
  const float* b1   = (const float*)d_in[15];
  const float* W2   = (const float*)d_in[16];
  const float* b2   = (const float*)d_in[17];
  const float* W3   = (const float*)d_in[18];
  const float* b3   = (const float*)d_in[19];

  char* ws = (char*)d_ws;
  if (ws_size < WS_NEED) return;

  _Float16* w0s  = (_Float16*)(ws + O_W0);
  _Float16* w1s  = (_Float16*)(ws + O_W1);
  float* bias0   = (float*)(ws + O_B0);
  float* bias1   = (float*)(ws + O_B1);
  float* peg     = (float*)(ws + O_PE);
  float* h1l     = (float*)(ws + O_H1);
  _Float16* ring = (_Float16*)(ws + O_RING);
  int* cnt       = (int*)(ws + O_CNT);

  hipMemsetAsync(ws + O_CNT, 0, 16384, stream);
  hipLaunchKernelGGL(k_bias, dim3(1), dim3(512), 0, stream, bih0, bhh0, bgcn, bte, Wih0, bih1, bhh1, bias0, bias1);
  hipLaunchKernelGGL(k_pe, dim3(2000), dim3(256), 0, stream, Wih0, bias0, peg);
  hipLaunchKernelGGL(k_wswz0n, dim3(384), dim3(256), 0, stream, Wgcn, Wte, Wih0, Whh0, w0s);
  hipLaunchKernelGGL(k_wswz1n, dim3(512), dim3(256), 0, stream, Wih1, Whh1, w1s);
  hipLaunchKernelGGL(k_lstm5, dim3(64), dim3(512), 0, stream, xs, xtc, w0s, w1s, peg, bias1, ring, cnt, h1l);
  hipLaunchKernelGGL(k_mlp, dim3(512), dim3(128), 0, stream, h1l, W1, b1, W2, b2, W3, b3, (float*)d_out);
}